// Round 11
// baseline (331.040 us; speedup 1.0000x reference)
//
#include <hip/hip_runtime.h>

#define N_NODES 10000
#define N_EDGES 640000

__device__ __forceinline__ float bf2f(unsigned int u) {
    union { unsigned int i; float f; } v; v.i = u << 16; return v.f;
}
__device__ __forceinline__ unsigned short f2bf(float f) {
    union { float f; unsigned int i; } v; v.f = f;
    unsigned int x = v.i;
    return (unsigned short)((x + 0x7fffu + ((x >> 16) & 1u)) >> 16);
}
__device__ __forceinline__ float scrub(float v) {
    return (v == v && fabsf(v) < 1e6f) ? v : 0.f;
}

// dtype-branched load of float tensor element i
template <bool BF16>
__device__ __forceinline__ float ldf(const void* p, int i) {
    if (BF16) return scrub(bf2f(((const unsigned short*)p)[i]));
    else      return scrub(((const float*)p)[i]);
}

// per-wave edge-dtype detection from this wave's own odd words.
// int32 layout: odd words are node ids, P(all 64 == 0) = 1e-4^64 ~ 0.
// int64 layout: odd words are hi-words == 0 always.
__device__ __forceinline__ int edge_step(int hi_word) {
    return (__ballot(hi_word != 0) != 0ull) ? 1 : 2;
}

// ---- K1: degree counts, both directions (grid exactly 2500x256) ----
__global__ __launch_bounds__(256) void k_count(const int* __restrict__ ei,
                                               int* __restrict__ cnt0,
                                               int* __restrict__ cnt1) {
    int e = blockIdx.x * 256 + threadIdx.x;        // always < N_EDGES
    int step = edge_step(ei[2 * e + 1]);
    int s = ei[e * step];
    int d = ei[N_EDGES * step + e * step];
    if ((unsigned)s >= N_NODES || (unsigned)d >= N_NODES) return;
    atomicAdd(&cnt0[d], 1);   // dir0: aggregate x[src] at dst
    atomicAdd(&cnt1[s], 1);   // dir1: aggregate x[dst] at src
}

// ---- K2: shfl exclusive scan (validated r9/r10) + sentinel total.
// r11: block 0 additionally computes dflag (f32-vs-bf16 stats on x). ----
__global__ __launch_bounds__(1024) void k_scan(const int* __restrict__ cnt_base,
                                               int* __restrict__ off_base,
                                               const unsigned int* __restrict__ xw,
                                               int* __restrict__ dflag) {
    const int* cnt = cnt_base + blockIdx.x * N_NODES;
    int* off = off_base + blockIdx.x * (N_NODES + 1);
    __shared__ int wsum[16];
    __shared__ int wexc[16];
    __shared__ int dcnt_s;
    int t = threadIdx.x;
    int lane = t & 63, wid = t >> 6;
    int c[10];
    int s = 0;
    int base_i = t * 10;
#pragma unroll
    for (int i = 0; i < 10; ++i) {
        int idx = base_i + i;
        c[i] = (idx < N_NODES) ? cnt[idx] : 0;
        s += c[i];
    }
    int v = s;                       // wave-inclusive scan of per-thread sums
    for (int d = 1; d < 64; d <<= 1) {
        int u = __shfl_up(v, d, 64);
        if (lane >= d) v += u;
    }
    if (lane == 63) wsum[wid] = v;
    __syncthreads();
    if (t < 16) {
        int acc = 0;
        for (int i = 0; i < t; ++i) acc += wsum[i];
        wexc[t] = acc;
    }
    __syncthreads();
    int run = wexc[wid] + (v - s);   // exclusive prefix for this thread's first elem
#pragma unroll
    for (int i = 0; i < 10; ++i) {
        int idx = base_i + i;
        if (idx < N_NODES) off[idx] = run;
        run += c[i];
    }
    if (t == 1023) off[N_NODES] = run;   // total (sentinel)

    // dflag stats (block 0 only): bf16 data -> lo-halfword exp in [96,160] ~100%
    if (blockIdx.x == 0) {
        if (t == 0) dcnt_s = 0;
        __syncthreads();
        int good = 0;
        for (int i = t; i < 4096; i += 1024) {
            unsigned int e = (xw[i] >> 7) & 0xFFu;
            if (e >= 96u && e <= 160u) good++;
        }
        atomicAdd(&dcnt_s, good);
        __syncthreads();
        if (t == 0) dflag[0] = (dcnt_s > 2458) ? 1 : 0;   // >60% -> bf16
    }
}

// ---- K3: fill BOTH CSR buckets in one ei pass (validated r10).
// Reverse-fill via atomicSub on cnt (destroys cnt; degrees from off-diffs). --
__global__ __launch_bounds__(256) void k_fill_both(const int* __restrict__ ei,
                                                   const int* __restrict__ off0,
                                                   const int* __restrict__ off1,
                                                   int* __restrict__ cnt0,
                                                   int* __restrict__ cnt1,
                                                   int* __restrict__ adj0,
                                                   int* __restrict__ adj1) {
    int e = blockIdx.x * 256 + threadIdx.x;        // always < N_EDGES
    int step = edge_step(ei[2 * e + 1]);
    int s = ei[e * step];
    int d = ei[N_EDGES * step + e * step];
    if ((unsigned)s >= N_NODES || (unsigned)d >= N_NODES) return;
    int p0 = atomicSub(&cnt0[d], 1) - 1;   // unique slot in [0, cnt0[d])
    int p1 = atomicSub(&cnt1[s], 1) - 1;
    adj0[off0[d] + p0] = s;
    adj1[off1[s] + p1] = d;
}

// ---- K4 (r11): dual-direction fused mean-aggregate + GEMM, single dispatch.
// out = bias_all + x@Wself + agg0@(0.5*Ws2d) + agg1@(0.5*Wd2s)
// Built from r10-proven parts: gather loop (x2), 4-chain phase 2 (3 terms/k).
template <bool BF16>
__device__ __forceinline__ float gather_half_mean(const void* x, const int* adj,
                                                  int o, int c, int n) {
    float a0 = 0.f, a1 = 0.f, a2 = 0.f, a3 = 0.f;
    float a4 = 0.f, a5 = 0.f, a6 = 0.f, a7 = 0.f;
    int j = 0;
    for (; j + 8 <= c; j += 8) {
        int i0 = adj[o + j + 0];
        int i1 = adj[o + j + 1];
        int i2 = adj[o + j + 2];
        int i3 = adj[o + j + 3];
        int i4 = adj[o + j + 4];
        int i5 = adj[o + j + 5];
        int i6 = adj[o + j + 6];
        int i7 = adj[o + j + 7];
        bool v0 = (unsigned)i0 < N_NODES, v1 = (unsigned)i1 < N_NODES;
        bool v2 = (unsigned)i2 < N_NODES, v3 = (unsigned)i3 < N_NODES;
        bool v4 = (unsigned)i4 < N_NODES, v5 = (unsigned)i5 < N_NODES;
        bool v6 = (unsigned)i6 < N_NODES, v7 = (unsigned)i7 < N_NODES;
        float f0 = ldf<BF16>(x, (v0 ? i0 : 0) * 128 + n);
        float f1 = ldf<BF16>(x, (v1 ? i1 : 0) * 128 + n);
        float f2 = ldf<BF16>(x, (v2 ? i2 : 0) * 128 + n);
        float f3 = ldf<BF16>(x, (v3 ? i3 : 0) * 128 + n);
        float f4 = ldf<BF16>(x, (v4 ? i4 : 0) * 128 + n);
        float f5 = ldf<BF16>(x, (v5 ? i5 : 0) * 128 + n);
        float f6 = ldf<BF16>(x, (v6 ? i6 : 0) * 128 + n);
        float f7 = ldf<BF16>(x, (v7 ? i7 : 0) * 128 + n);
        a0 += v0 ? f0 : 0.f;
        a1 += v1 ? f1 : 0.f;
        a2 += v2 ? f2 : 0.f;
        a3 += v3 ? f3 : 0.f;
        a4 += v4 ? f4 : 0.f;
        a5 += v5 ? f5 : 0.f;
        a6 += v6 ? f6 : 0.f;
        a7 += v7 ? f7 : 0.f;
    }
    for (; j < c; ++j) {
        int idx = adj[o + j];
        if ((unsigned)idx < N_NODES) a0 += ldf<BF16>(x, idx * 128 + n);
    }
    float asum = ((a0 + a1) + (a2 + a3)) + ((a4 + a5) + (a6 + a7));
    return asum * (0.5f / (float)(c > 0 ? c : 1));
}

template <bool BF16>
__device__ void aggemm_body(const void* x, const int* off0, const int* adj0,
                            const int* off1, const int* adj1,
                            const void* Wself, const void* Ws2d, const void* Wd2s,
                            const void* bself, const void* bs2d, const void* bd2s,
                            void* out) {
    __shared__ float agg0[2][128];
    __shared__ float agg1[2][128];
    __shared__ float xr[2][128];
    int tid = threadIdx.x;
    int mloc = tid >> 7;
    int n = tid & 127;
    int m = blockIdx.x * 2 + mloc;

    // phase 1: both directions' 0.5*mean (r10-proven gather, run twice)
    {
        int o = off0[m];
        int c = off0[m + 1] - o;
        if (o < 0) o = 0;
        if (c < 0) c = 0;
        agg0[mloc][n] = gather_half_mean<BF16>(x, adj0, o, c, n);
    }
    {
        int o = off1[m];
        int c = off1[m + 1] - o;
        if (o < 0) o = 0;
        if (c < 0) c = 0;
        agg1[mloc][n] = gather_half_mean<BF16>(x, adj1, o, c, n);
    }
    xr[mloc][n] = ldf<BF16>(x, m * 128 + n);
    __syncthreads();

    // phase 2: 4 independent FMA chains, 3 terms per k
    float accA = ldf<BF16>(bself, n) + 0.5f * (ldf<BF16>(bs2d, n) + ldf<BF16>(bd2s, n));
    float accB = 0.f, accC = 0.f, accD = 0.f;
    for (int k = 0; k < 128; k += 4) {
        accA += xr[mloc][k + 0] * ldf<BF16>(Wself, (k + 0) * 128 + n);
        accB += xr[mloc][k + 1] * ldf<BF16>(Wself, (k + 1) * 128 + n);
        accC += xr[mloc][k + 2] * ldf<BF16>(Wself, (k + 2) * 128 + n);
        accD += xr[mloc][k + 3] * ldf<BF16>(Wself, (k + 3) * 128 + n);
        accA += agg0[mloc][k + 0] * ldf<BF16>(Ws2d, (k + 0) * 128 + n);
        accB += agg0[mloc][k + 1] * ldf<BF16>(Ws2d, (k + 1) * 128 + n);
        accC += agg0[mloc][k + 2] * ldf<BF16>(Ws2d, (k + 2) * 128 + n);
        accD += agg0[mloc][k + 3] * ldf<BF16>(Ws2d, (k + 3) * 128 + n);
        accA += agg1[mloc][k + 0] * ldf<BF16>(Wd2s, (k + 0) * 128 + n);
        accB += agg1[mloc][k + 1] * ldf<BF16>(Wd2s, (k + 1) * 128 + n);
        accC += agg1[mloc][k + 2] * ldf<BF16>(Wd2s, (k + 2) * 128 + n);
        accD += agg1[mloc][k + 3] * ldf<BF16>(Wd2s, (k + 3) * 128 + n);
    }
    float acc = (accA + accB) + (accC + accD);
    if (BF16) ((unsigned short*)out)[m * 128 + n] = f2bf(acc);
    else      ((float*)out)[m * 128 + n] = acc;
}

__global__ __launch_bounds__(256) void k_aggemm(const void* x, const int* dflag,
                                                const int* off0, const int* adj0,
                                                const int* off1, const int* adj1,
                                                const void* Wself, const void* Ws2d,
                                                const void* Wd2s,
                                                const void* bself, const void* bs2d,
                                                const void* bd2s, void* out) {
    if (dflag[0])
        aggemm_body<true>(x, off0, adj0, off1, adj1, Wself, Ws2d, Wd2s,
                          bself, bs2d, bd2s, out);
    else
        aggemm_body<false>(x, off0, adj0, off1, adj1, Wself, Ws2d, Wd2s,
                           bself, bs2d, bd2s, out);
}

// ---- sentinel: decodable failure diagnosis via absmax ----
__global__ __launch_bounds__(256) void k_sentinel(float* __restrict__ out, float v) {
    int i = blockIdx.x * 256 + threadIdx.x;
    if (i < 640000) out[i] = v;
}

extern "C" void kernel_launch(void* const* d_in, const int* in_sizes, int n_in,
                              void* d_out, int out_size, void* d_ws, size_t ws_size,
                              hipStream_t stream) {
    const void* x = d_in[0];
    const int* ei = (const int*)d_in[1];
    const void* Ws2d = d_in[2];
    const void* bs2d = d_in[3];
    const void* Wd2s = d_in[4];
    const void* bd2s = d_in[5];
    const void* Wself = d_in[6];
    const void* bself = d_in[7];

    bool sizes_ok = (n_in == 8)
        && in_sizes[0] == 1280000
        && (in_sizes[1] == 1280000 || in_sizes[1] == 2560000)
        && in_sizes[2] == 16384 && in_sizes[3] == 128
        && in_sizes[4] == 16384 && in_sizes[5] == 128
        && in_sizes[6] == 16384 && in_sizes[7] == 128
        && out_size == 1280000;
    size_t ws_need = (size_t)(40032 + 2 * 640000) * 4;   // 5.28 MB (proven r10)
    if (ws_size < ws_need) {
        k_sentinel<<<2500, 256, 0, stream>>>((float*)d_out, 1000.0f);
        return;
    }
    if (!sizes_ok) {
        k_sentinel<<<2500, 256, 0, stream>>>((float*)d_out, 2000.0f);
        return;
    }

    int* ws = (int*)d_ws;
    int* cnt0  = ws;             // [10000]
    int* cnt1  = ws + 10000;     // [10000]
    int* dflag = ws + 20001;     // [1]   (same slot as r10)
    int* off0  = ws + 20016;     // [10001]  (off1 contiguous for k_scan)
    int* off1  = ws + 30017;     // [10001]
    int* adj0  = ws + 40032;     // [640000]
    int* adj1  = ws + 680032;    // [640000]

    hipMemsetAsync(ws, 0, 20002 * sizeof(int), stream);  // cnt0, cnt1, flags

    k_count<<<N_EDGES / 256, 256, 0, stream>>>(ei, cnt0, cnt1);
    k_scan<<<2, 1024, 0, stream>>>(cnt0, off0, (const unsigned int*)x, dflag);
    k_fill_both<<<N_EDGES / 256, 256, 0, stream>>>(ei, off0, off1,
                                                   cnt0, cnt1, adj0, adj1);
    k_aggemm<<<N_NODES / 2, 256, 0, stream>>>(x, dflag, off0, adj0, off1, adj1,
                                              Wself, Ws2d, Wd2s,
                                              bself, bs2d, bd2s, d_out);
}